// Round 2
// baseline (715.788 us; speedup 1.0000x reference)
//
#include <hip/hip_runtime.h>
#include <math.h>

#define N_TOK 1024   // b*c = 4*256
#define DIN   1024
#define DHID  2048   // DIM_HIDDEN * NUM_HEADS
#define NSUB  256
#define SKDIM 256    // DIM_HIDDEN/2
#define NH    4
#define TOPK  32

#define TILE 64
#define BKQ  16

// ---------------- q = x @ Wq^T  (M=1024, N=2048, K=1024), fp64 accumulate ----------------
// fp64 end-to-end on the selection path: top-k is discontinuous, and fp32
// accumulation-order noise (~1e-6) vs rank-32 score spacing (~8e-3) flips
// ~1-2 selections per run vs the np (fp64) reference. fp64 makes flips
// measure-zero; output path (gather) stays fp32.
__global__ __launch_bounds__(256) void gemm_q(const float* __restrict__ X,
                                              const float* __restrict__ W,
                                              double* __restrict__ Q) {
  __shared__ float As[BKQ][TILE + 4];
  __shared__ float Bs[BKQ][TILE + 4];
  const int tid = threadIdx.x;
  const int gm0 = blockIdx.y * TILE;
  const int gn0 = blockIdx.x * TILE;
  const int lr = tid >> 2;          // 0..63
  const int lc = (tid & 3) << 2;    // 0,4,8,12
  const int tx = tid & 15;
  const int ty = tid >> 4;
  double acc[4][4] = {};
  for (int k0 = 0; k0 < DIN; k0 += BKQ) {
    float4 av = *(const float4*)&X[(size_t)(gm0 + lr) * DIN + k0 + lc];
    float4 bv = *(const float4*)&W[(size_t)(gn0 + lr) * DIN + k0 + lc];
    __syncthreads();
    As[lc + 0][lr] = av.x; As[lc + 1][lr] = av.y; As[lc + 2][lr] = av.z; As[lc + 3][lr] = av.w;
    Bs[lc + 0][lr] = bv.x; Bs[lc + 1][lr] = bv.y; Bs[lc + 2][lr] = bv.z; Bs[lc + 3][lr] = bv.w;
    __syncthreads();
#pragma unroll
    for (int kk = 0; kk < BKQ; kk++) {
      float4 a = *(const float4*)&As[kk][tx << 2];
      float4 b = *(const float4*)&Bs[kk][ty << 2];
      double a0 = a.x, a1 = a.y, a2 = a.z, a3 = a.w;
      double b0 = b.x, b1 = b.y, b2 = b.z, b3 = b.w;
      acc[0][0] += a0 * b0; acc[0][1] += a0 * b1; acc[0][2] += a0 * b2; acc[0][3] += a0 * b3;
      acc[1][0] += a1 * b0; acc[1][1] += a1 * b1; acc[1][2] += a1 * b2; acc[1][3] += a1 * b3;
      acc[2][0] += a2 * b0; acc[2][1] += a2 * b1; acc[2][2] += a2 * b2; acc[2][3] += a2 * b3;
      acc[3][0] += a3 * b0; acc[3][1] += a3 * b1; acc[3][2] += a3 * b2; acc[3][3] += a3 * b3;
    }
  }
#pragma unroll
  for (int i = 0; i < 4; i++)
#pragma unroll
    for (int j = 0; j < 4; j++)
      Q[(size_t)(gm0 + (tx << 2) + i) * DHID + gn0 + (ty << 2) + j] = acc[i][j];
}

// ---------------- BatchNorm stats over the 1024 token rows (fp64) ----------------
__global__ void bn_partial(const double* __restrict__ Q,
                           double* __restrict__ psum, double* __restrict__ psq) {
  const int col = blockIdx.x * 256 + threadIdx.x;   // 8 col-groups
  const int rg = blockIdx.y;                        // 16 row-groups of 64
  double s = 0.0, q2 = 0.0;
  for (int r = rg * 64; r < rg * 64 + 64; r++) {
    double v = Q[(size_t)r * DHID + col];
    s += v; q2 += v * v;
  }
  psum[rg * DHID + col] = s;
  psq[rg * DHID + col] = q2;
}

__global__ void bn_final(const double* __restrict__ psum, const double* __restrict__ psq,
                         double* __restrict__ mean, double* __restrict__ rstd) {
  const int col = blockIdx.x * 256 + threadIdx.x;
  double s = 0.0, q2 = 0.0;
  for (int rg = 0; rg < 16; rg++) { s += psum[rg * DHID + col]; q2 += psq[rg * DHID + col]; }
  double m = s * (1.0 / N_TOK);
  double var = q2 * (1.0 / N_TOK) - m * m;
  mean[col] = m;
  rstd[col] = 1.0 / sqrt(var + 1e-5);
}

// -------- scores (fp64): per (head,side)  S[m][k] = sum_d qnorm[m][base+d] * key[k][d] --------
__global__ __launch_bounds__(256) void scores_kernel(const double* __restrict__ Q,
    const double* __restrict__ mean, const double* __restrict__ rstd,
    const float* __restrict__ gamma, const float* __restrict__ beta,
    const float* __restrict__ keyl, const float* __restrict__ keyr,
    double* __restrict__ scorel, double* __restrict__ scorer) {
  __shared__ double As[BKQ][TILE + 2];
  __shared__ double Bs[BKQ][TILE + 2];
  const int tid = threadIdx.x;
  const int head = blockIdx.z >> 1;
  const int side = blockIdx.z & 1;
  const int base = head * 512 + side * 256;
  const float* __restrict__ key = side ? keyr : keyl;
  double* __restrict__ S = side ? scorer : scorel;
  const int gm0 = blockIdx.y * TILE;   // token tile (16)
  const int gn0 = blockIdx.x * TILE;   // subkey tile (4)
  const int lr = tid >> 2;
  const int lc = (tid & 3) << 2;
  const int tx = tid & 15;
  const int ty = tid >> 4;
  double acc[4][4] = {};
  for (int k0 = 0; k0 < SKDIM; k0 += BKQ) {
    const int c = base + k0 + lc;
    double qv[4], av[4];
#pragma unroll
    for (int u = 0; u < 4; u++) qv[u] = Q[(size_t)(gm0 + lr) * DHID + c + u];
#pragma unroll
    for (int u = 0; u < 4; u++)
      av[u] = (qv[u] - mean[c + u]) * rstd[c + u] * (double)gamma[c + u] + (double)beta[c + u];
    float4 bv = *(const float4*)&key[((size_t)(head * NSUB) + gn0 + lr) * SKDIM + k0 + lc];
    __syncthreads();
    As[lc + 0][lr] = av[0]; As[lc + 1][lr] = av[1]; As[lc + 2][lr] = av[2]; As[lc + 3][lr] = av[3];
    Bs[lc + 0][lr] = (double)bv.x; Bs[lc + 1][lr] = (double)bv.y;
    Bs[lc + 2][lr] = (double)bv.z; Bs[lc + 3][lr] = (double)bv.w;
    __syncthreads();
#pragma unroll
    for (int kk = 0; kk < BKQ; kk++) {
      double a0 = As[kk][(tx << 2) + 0], a1 = As[kk][(tx << 2) + 1];
      double a2 = As[kk][(tx << 2) + 2], a3 = As[kk][(tx << 2) + 3];
      double b0 = Bs[kk][(ty << 2) + 0], b1 = Bs[kk][(ty << 2) + 1];
      double b2 = Bs[kk][(ty << 2) + 2], b3 = Bs[kk][(ty << 2) + 3];
      acc[0][0] += a0 * b0; acc[0][1] += a0 * b1; acc[0][2] += a0 * b2; acc[0][3] += a0 * b3;
      acc[1][0] += a1 * b0; acc[1][1] += a1 * b1; acc[1][2] += a1 * b2; acc[1][3] += a1 * b3;
      acc[2][0] += a2 * b0; acc[2][1] += a2 * b1; acc[2][2] += a2 * b2; acc[2][3] += a2 * b3;
      acc[3][0] += a3 * b0; acc[3][1] += a3 * b1; acc[3][2] += a3 * b2; acc[3][3] += a3 * b3;
    }
  }
#pragma unroll
  for (int i = 0; i < 4; i++) {
    const int m = gm0 + (tx << 2) + i;
#pragma unroll
    for (int j = 0; j < 4; j++)
      S[((size_t)m * NH + head) * NSUB + gn0 + (ty << 2) + j] = acc[i][j];
  }
}

// ---------------- top-k + product top-k + softmax (fp64 compares) ----------------
__device__ __forceinline__ void bitonic_desc(volatile double* v, volatile int* idx,
                                             int n, int tid, int nthreads) {
  for (int k = 2; k <= n; k <<= 1) {
    for (int j = k >> 1; j > 0; j >>= 1) {
      __syncthreads();
      for (int i = tid; i < n; i += nthreads) {
        int ixj = i ^ j;
        if (ixj > i) {
          double a = v[i], b = v[ixj];
          bool up = ((i & k) == 0);           // descending overall
          bool sw = up ? (a < b) : (a > b);
          if (sw) {
            v[i] = b; v[ixj] = a;
            int t = idx[i]; idx[i] = idx[ixj]; idx[ixj] = t;
          }
        }
      }
    }
  }
  __syncthreads();
}

__global__ __launch_bounds__(256) void topk_kernel(const double* __restrict__ scorel,
                                                   const double* __restrict__ scorer,
                                                   float* __restrict__ wts,
                                                   int* __restrict__ sel) {
  const int bx = blockIdx.x;
  const int token = bx >> 2, head = bx & 3;
  const int tid = threadIdx.x;
  __shared__ double sv[256];
  __shared__ int    si[256];
  __shared__ double tlv[TOPK]; __shared__ int tli[TOPK];
  __shared__ double trv[TOPK]; __shared__ int tri[TOPK];
  __shared__ double ex[TOPK];
  __shared__ double ssum;

  const double* sl = scorel + ((size_t)token * NH + head) * NSUB;
  const double* sr = scorer + ((size_t)token * NH + head) * NSUB;

  // top-32 of left scores
  sv[tid] = sl[tid]; si[tid] = tid;
  bitonic_desc(sv, si, 256, tid, 256);
  if (tid < TOPK) { tlv[tid] = sv[tid]; tli[tid] = si[tid]; }
  __syncthreads();

  // top-32 of right scores
  sv[tid] = sr[tid]; si[tid] = tid;
  bitonic_desc(sv, si, 256, tid, 256);
  if (tid < TOPK) { trv[tid] = sv[tid]; tri[tid] = si[tid]; }
  __syncthreads();

  // staircase candidates: (i,j) with (i+1)(j+1) <= 32 -> 119 candidates, pad to 128.
  // (Any pair outside the staircase has >=32 pairs that dominate it by value AND
  // by flat index, so it can never enter the reference top-32, ties included.)
  // Reference quirk: product_indices broadcasts pair_idx[..., :, None], so the
  // gathered row index is idx_l[i]*256 + idx_r[i] (depends only on left rank i).
  if (tid < 128) {
    double v = -INFINITY; int id = 0;
    if (tid < 119) {
      int rem = tid, i = 0;
      for (;;) {
        int c = 32 / (i + 1);
        if (rem < c) break;
        rem -= c; i++;
      }
      v = tlv[i] + trv[rem];
      id = tli[i] * NSUB + tri[i];   // <-- i for both (reference broadcast quirk)
    }
    sv[tid] = v; si[tid] = id;
  }
  bitonic_desc(sv, si, 128, tid, 256);

  // softmax over the top 32 (sv sorted desc -> max is sv[0])
  double m = sv[0];
  if (tid < TOPK) ex[tid] = exp(sv[tid] - m);
  __syncthreads();
  if (tid == 0) {
    double s = 0.0;
    for (int i = 0; i < TOPK; i++) s += ex[i];
    ssum = s;
  }
  __syncthreads();
  if (tid < TOPK) {
    size_t o = ((size_t)token * NH + head) * TOPK + tid;
    wts[o] = (float)(ex[tid] / ssum);
    sel[o] = si[tid];
  }
}

// ---------------- weighted gather from value_table (fp32) ----------------
__global__ __launch_bounds__(256) void gather_kernel(const float* __restrict__ wts,
                                                     const int* __restrict__ sel,
                                                     const float* __restrict__ VT,
                                                     float* __restrict__ out) {
  __shared__ float w_s[NH * TOPK];
  __shared__ int   i_s[NH * TOPK];
  const int token = blockIdx.x;
  const int tid = threadIdx.x;
  if (tid < NH * TOPK) {
    w_s[tid] = wts[(size_t)token * NH * TOPK + tid];
    i_s[tid] = sel[(size_t)token * NH * TOPK + tid];
  }
  __syncthreads();
  const int d = tid << 2;
  float4 acc = make_float4(0.f, 0.f, 0.f, 0.f);
#pragma unroll 8
  for (int p = 0; p < NH * TOPK; p++) {
    float w = w_s[p];
    float4 v = *(const float4*)&VT[(size_t)i_s[p] * DIN + d];
    acc.x += w * v.x; acc.y += w * v.y; acc.z += w * v.z; acc.w += w * v.w;
  }
  *(float4*)&out[(size_t)token * DIN + d] = acc;
}

extern "C" void kernel_launch(void* const* d_in, const int* in_sizes, int n_in,
                              void* d_out, int out_size, void* d_ws, size_t ws_size,
                              hipStream_t stream) {
  const float* x     = (const float*)d_in[0];
  const float* Wq    = (const float*)d_in[1];
  const float* gamma = (const float*)d_in[2];
  const float* beta  = (const float*)d_in[3];
  const float* keyl  = (const float*)d_in[4];
  const float* keyr  = (const float*)d_in[5];
  const float* vt    = (const float*)d_in[6];
  float* out = (float*)d_out;

  double* wsd = (double*)d_ws;
  double* qd     = wsd;                       // 1024*2048  = 2,097,152 doubles
  double* psum   = wsd + 2097152;             // 16*2048    = 32,768
  double* psq    = wsd + 2129920;             // 32,768
  double* meand  = wsd + 2162688;             // 2048
  double* rstdd  = wsd + 2164736;             // 2048
  double* scl    = wsd + 2166784;             // 1024*4*256 = 1,048,576
  double* scr    = wsd + 3215360;             // 1,048,576
  float*  wts    = (float*)(wsd + 4263936);   // 131,072 floats
  int*    sel    = (int*)(wts + 131072);      // 131,072 ints

  gemm_q<<<dim3(32, 16), 256, 0, stream>>>(x, Wq, qd);
  bn_partial<<<dim3(8, 16), 256, 0, stream>>>(qd, psum, psq);
  bn_final<<<8, 256, 0, stream>>>(psum, psq, meand, rstdd);
  scores_kernel<<<dim3(4, 16, 8), 256, 0, stream>>>(qd, meand, rstdd, gamma, beta,
                                                    keyl, keyr, scl, scr);
  topk_kernel<<<N_TOK * NH, 256, 0, stream>>>(scl, scr, wts, sel);
  gather_kernel<<<N_TOK, 256, 0, stream>>>(wts, sel, vt, out);
}